// Round 1
// baseline (238.208 us; speedup 1.0000x reference)
//
#include <hip/hip_runtime.h>

// GlimpseSensor: out[b,p,c,j,k] = mask * x[b, c, base_r(b,p) + j<<p, base_c(b,p) + k<<p]
// base_* = floor(0.5*(l+1)*H) - (64<<p)/2 ; mask = in-bounds(row) & in-bounds(col)
//
// Shapes fixed by setup_inputs(): x (64,3,512,512) f32, l (64,2) f32,
// initial_patch_size=64, num_patches=3, scaling_factor=2.
// size_p = 64*2^p, ds = 64 -> offs[j] = (j*size_p)//64 = j << p (exact).

namespace {
constexpr int kB  = 64;
constexpr int kC  = 3;
constexpr int kH  = 512;
constexpr int kW  = 512;
constexpr int kDS = 64;   // initial_patch_size (output patch side)
constexpr int kP  = 3;    // num_patches
}  // namespace

__global__ __launch_bounds__(256) void glimpse_kernel(
    const float* __restrict__ x, const float* __restrict__ l,
    float* __restrict__ out) {
  int idx = blockIdx.x * blockDim.x + threadIdx.x;
  constexpr int K4 = kDS / 4;  // 16 float4 per output row
  int k4 = idx & (K4 - 1);
  int j  = (idx / K4) & (kDS - 1);
  int t  = idx / (K4 * kDS);
  int c  = t % kC;
  t /= kC;
  int p  = t % kP;
  int b  = t / kP;
  if (b >= kB) return;

  // Bit-identical to jnp: floor(0.5f*(l+1.0f)*512.0f); both scalings are
  // exact powers of two, only (l+1.0f) rounds — same as the fp32 reference.
  float lr = l[b * 2 + 0];
  float lc = l[b * 2 + 1];
  int half   = (kDS << p) >> 1;                                // size/2
  int base_r = (int)floorf(0.5f * (lr + 1.0f) * (float)kH) - half;
  int base_c = (int)floorf(0.5f * (lc + 1.0f) * (float)kH) - half;

  int   row   = base_r + (j << p);
  float rmask = (row >= 0 && row < kH) ? 1.0f : 0.0f;
  int   rcl   = min(max(row, 0), kH - 1);                      // clip like ref
  const float* xrow = x + (((size_t)b * kC + c) * kH + rcl) * (size_t)kW;

  int k0 = k4 * 4;
  float4 v;
  float* vv = reinterpret_cast<float*>(&v);
#pragma unroll
  for (int i = 0; i < 4; ++i) {
    int   col   = base_c + ((k0 + i) << p);
    float cmask = (col >= 0 && col < kW) ? 1.0f : 0.0f;
    int   ccl   = min(max(col, 0), kW - 1);
    vv[i] = xrow[ccl] * rmask * cmask;                         // clip + mask
  }

  size_t oidx = ((((size_t)b * kP + p) * kC + c) * (size_t)kDS + j) * kDS + k0;
  *reinterpret_cast<float4*>(out + oidx) = v;
}

extern "C" void kernel_launch(void* const* d_in, const int* in_sizes, int n_in,
                              void* d_out, int out_size, void* d_ws, size_t ws_size,
                              hipStream_t stream) {
  const float* x = (const float*)d_in[0];
  const float* l = (const float*)d_in[1];
  float* out = (float*)d_out;

  constexpr int total = kB * kP * kC * kDS * (kDS / 4);  // 589,824 threads
  glimpse_kernel<<<dim3((total + 255) / 256), dim3(256), 0, stream>>>(x, l, out);
}